// Round 14
// baseline (355.131 us; speedup 1.0000x reference)
//
#include <hip/hip_runtime.h>
#include <hip/hip_bf16.h>

#define DI __device__ __forceinline__

typedef __attribute__((ext_vector_type(8))) __bf16 bf16x8;
typedef __attribute__((ext_vector_type(4))) float f32x4;
typedef __attribute__((ext_vector_type(4))) unsigned short u16x4;
typedef __attribute__((ext_vector_type(8))) unsigned short u16x8;

DI unsigned short f2bs(float f) {
  __hip_bfloat16 h = __float2bfloat16(f);
  return __builtin_bit_cast(unsigned short, h);
}
DI float bs2f(unsigned short s) {
  return __bfloat162float(__builtin_bit_cast(__hip_bfloat16, s));
}
DI f32x4 mfma16(bf16x8 a, bf16x8 b, f32x4 c) {
  return __builtin_amdgcn_mfma_f32_16x16x32_bf16(a, b, c, 0, 0, 0);
}
DI void g2lds16(const void* g, void* l) {
  __builtin_amdgcn_global_load_lds(
      (__attribute__((address_space(1))) void*)(unsigned long long)g,
      (__attribute__((address_space(3))) void*)l, 16, 0, 0);
}
#define SB __builtin_amdgcn_sched_barrier(0)

// ---------------- weight transpose f32[K,N] -> bf16[N,K] ----------------
__global__ __launch_bounds__(256) void k_transw(const float* __restrict__ W,
                                                unsigned short* __restrict__ Wt,
                                                int K, int N) {
  __shared__ float tile[64][65];
  int tk = blockIdx.x * 64, tn = blockIdx.y * 64;
  int t = threadIdx.x;
#pragma unroll
  for (int i = 0; i < 16; ++i) {
    int idx = t + i * 256;
    int r = idx >> 6, c = idx & 63;
    tile[r][c] = W[(size_t)(tk + r) * N + tn + c];
  }
  __syncthreads();
#pragma unroll
  for (int i = 0; i < 16; ++i) {
    int idx = t + i * 256;
    int n = idx >> 6, kk = idx & 63;
    Wt[(size_t)(tn + n) * K + tk + kk] = f2bs(tile[kk][n]);
  }
}

// ---------------- bias concat [bq|bk|bv|bg] -> bcat[2048] ----------------
__global__ __launch_bounds__(256) void k_bcat(const float* __restrict__ bq,
                                              const float* __restrict__ bk,
                                              const float* __restrict__ bv,
                                              const float* __restrict__ bg,
                                              float* __restrict__ bcat) {
  int t = blockIdx.x * 256 + threadIdx.x;
  const float* src = t < 512 ? bq : t < 1024 ? bk : t < 1536 ? bv : bg;
  bcat[t] = src[t & 511];
}

// ---------------- bias transpose: coalesced LDS transpose, mask folded ----------------
// out: biasT [B,H,Nq,Nk'] bf16, within each 32-col chunk order (c0,c16,c1,c17,...)
__global__ __launch_bounds__(256) void k_btrans2(const float* __restrict__ bias,
                                                 const unsigned char* __restrict__ mask,
                                                 unsigned short* __restrict__ biasT) {
  __shared__ unsigned short lsT[8][2048];  // [h][col] bf16, 32KB
  __shared__ unsigned char lsM[2048];
  int bid = blockIdx.x;  // b*2048 + row
  int b = bid >> 11, row = bid & 2047;
  int t = threadIdx.x;
  size_t rowoff = (size_t)bid * 2048;
  const float4* src4 = (const float4*)(bias + rowoff * 8);
#pragma unroll
  for (int i = 0; i < 16; ++i) {
    int idx = i * 256 + t;
    float4 f = src4[idx];
    int flat = idx * 4;
    int col = flat >> 3;
    int h0 = flat & 7;
    lsT[h0 + 0][col] = f2bs(f.x);
    lsT[h0 + 1][col] = f2bs(f.y);
    lsT[h0 + 2][col] = f2bs(f.z);
    lsT[h0 + 3][col] = f2bs(f.w);
  }
  ((uint2*)lsM)[t] = ((const uint2*)(mask + rowoff))[t];
  __syncthreads();
  int h = t >> 5, j = t & 31;
  const unsigned short BN = f2bs(-1e30f);
  unsigned short* dst = biasT + ((size_t)(b * 8 + h) * 2048 + row) * 2048;
#pragma unroll
  for (int s = 0; s < 8; ++s) {
    int ebase = s * 256 + j * 8;
    int c32 = (ebase >> 5) << 5;
    int p0 = ebase & 31;
    u16x8 o;
#pragma unroll
    for (int qq = 0; qq < 8; ++qq) {
      int p = p0 + qq;
      int c = c32 + (p >> 1) + ((p & 1) << 4);
      o[qq] = lsM[c] ? BN : lsT[h][c];
    }
    *(u16x8*)(dst + ebase) = o;
  }
}

// ---------------- LayerNorm f32[rows,512] -> bf16 ----------------
__global__ __launch_bounds__(256) void k_ln(const float* __restrict__ x,
                                            const float* __restrict__ g,
                                            const float* __restrict__ b,
                                            unsigned short* __restrict__ y) {
  int row = blockIdx.x, t = threadIdx.x;
  const float* xr = x + (size_t)row * 512;
  float a0 = xr[t], a1 = xr[t + 256];
  float s1 = a0 + a1, s2 = a0 * a0 + a1 * a1;
#pragma unroll
  for (int o = 32; o > 0; o >>= 1) {
    s1 += __shfl_down(s1, o);
    s2 += __shfl_down(s2, o);
  }
  __shared__ float r1[4], r2[4], bc[2];
  int w = t >> 6, l = t & 63;
  if (l == 0) { r1[w] = s1; r2[w] = s2; }
  __syncthreads();
  if (t == 0) {
    float t1 = r1[0] + r1[1] + r1[2] + r1[3];
    float t2 = r2[0] + r2[1] + r2[2] + r2[3];
    float m = t1 / 512.f;
    float v = t2 / 512.f - m * m;
    bc[0] = m;
    bc[1] = rsqrtf(v + 1e-5f);
  }
  __syncthreads();
  float m = bc[0], inv = bc[1];
  y[(size_t)row * 512 + t] = f2bs((a0 - m) * inv * g[t] + b[t]);
  y[(size_t)row * 512 + t + 256] = f2bs((a1 - m) * inv * g[t + 256] + b[t + 256]);
}

// ---------------- GEMM: C[M,N] = A[M,K](bf16) * Bt[N,K]^T + bias ----------------
template <int BM>
__global__ __launch_bounds__(256) void k_gemm(
    const unsigned short* __restrict__ A, const unsigned short* __restrict__ Bt,
    const float* __restrict__ bias, int M, int N, int K, int mode,
    float* __restrict__ outf, unsigned short* __restrict__ outh,
    const float* __restrict__ add1, const float* __restrict__ add2,
    unsigned short* __restrict__ vtout) {
  constexpr int MI = BM / 32;
  __shared__ __align__(16) unsigned short lA[BM * 64];
  __shared__ __align__(16) unsigned short lB[64 * 64];
  int t = threadIdx.x, w = t >> 6, l = t & 63;
  int l15 = l & 15, lg = l >> 4;
  int m0 = blockIdx.x * BM, n0 = blockIdx.y * 64;
  int wm = (w >> 1) * (BM / 2), wn = (w & 1) * 32;
  f32x4 acc[MI][2] = {};
  int sr = l >> 3, scb = (l & 7) * 16;
  for (int k0 = 0; k0 < K; k0 += 64) {
#pragma unroll
    for (int c = 0; c < MI; ++c) {
      int row = w * (BM / 4) + sr + c * 8;
      g2lds16((const char*)A + ((size_t)(m0 + row) * K + k0) * 2 + scb,
              (char*)lA + w * (BM / 4) * 128 + c * 1024);
    }
#pragma unroll
    for (int c = 0; c < 2; ++c) {
      int row = w * 16 + sr + c * 8;
      g2lds16((const char*)Bt + ((size_t)(n0 + row) * K + k0) * 2 + scb,
              (char*)lB + w * 2048 + c * 1024);
    }
    __syncthreads();
#pragma unroll
    for (int kc = 0; kc < 2; ++kc) {
      bf16x8 af[MI], bfr[2];
#pragma unroll
      for (int i = 0; i < MI; ++i)
        af[i] = *(const bf16x8*)((const char*)lA + (wm + i * 16 + l15) * 128 + kc * 64 + lg * 16);
#pragma unroll
      for (int j = 0; j < 2; ++j)
        bfr[j] = *(const bf16x8*)((const char*)lB + (wn + j * 16 + l15) * 128 + kc * 64 + lg * 16);
#pragma unroll
      for (int i = 0; i < MI; ++i)
#pragma unroll
        for (int j = 0; j < 2; ++j)
          acc[i][j] = mfma16(af[i], bfr[j], acc[i][j]);
    }
    __syncthreads();
  }
#pragma unroll
  for (int i = 0; i < MI; ++i) {
#pragma unroll
    for (int j = 0; j < 2; ++j) {
      int col = n0 + wn + j * 16 + l15;
      int row0 = m0 + wm + i * 16 + lg * 4;
      float vals[4];
#pragma unroll
      for (int r = 0; r < 4; ++r) vals[r] = acc[i][j][r] + bias[col];
      if (mode == 6) {
        int sel = col >> 9, c5 = col & 511;
        if (sel == 2) {
          int hh = c5 >> 6, dd = c5 & 63, bb = row0 >> 11, nn = row0 & 2047;
          u16x4 pk;
#pragma unroll
          for (int r = 0; r < 4; ++r) pk[r] = f2bs(vals[r]);
          *(u16x4*)(vtout + (((size_t)(bb * 8 + hh) * 64 + dd) * 2048 + nn)) = pk;
        } else {
#pragma unroll
          for (int r = 0; r < 4; ++r) {
            size_t idx = (size_t)(row0 + r) * 512 + c5;
            if (sel == 0) outh[idx] = f2bs(vals[r] * 0.125f);
            else if (sel == 1) outh[2097152 + idx] = f2bs(vals[r]);
            else outf[idx] = bs2f(A[idx]) * (1.f / (1.f + __expf(-vals[r])));
          }
        }
      } else {
#pragma unroll
        for (int r = 0; r < 4; ++r) {
          size_t idx = (size_t)(row0 + r) * N + col;
          if (mode == 3) outf[idx] = vals[r] + add1[idx] + add2[idx];
          else if (mode == 4) outh[idx] = f2bs(0.5f * vals[r] * (1.f + erff(vals[r] * 0.70710678f)));
          else outf[idx] = vals[r] + add1[idx];
        }
      }
    }
  }
}

// ---------------- flash attention v13: SB-pinned 2-chain load burst ----------------
// = attn5's validated body (biasT bf16 planes, static-max exp, MFMA rowsum, per-wave
// ls_p parity, NO block barriers) with both iterations' loads (8x K/V b128 + 8x bias
// dword) issued in one sched_barrier(0)-fenced window BEFORE the two computes.
// (256,4) -> 128-VGPR cap: the ~120-reg double buffer fits (R12's failure was cap 64).
// block = (b, 16q, 4-head half, k-half); grid 1024 -> 4 blocks/CU, 16 waves/CU.
template <int NKS>
__global__ __launch_bounds__(256, 4) void k_attn13(
    const unsigned short* __restrict__ q, const unsigned short* __restrict__ kk,
    const unsigned short* __restrict__ vt, const unsigned short* __restrict__ biasT,
    unsigned short* __restrict__ opart, float* __restrict__ lpart) {
  __shared__ unsigned short ls_p[2][4][16][36];
  int bid = blockIdx.x;
  int b = bid & 1;                  // XCD = bid%8 -> each XCD serves one batch
  int rest = bid >> 1;
  int qt = rest & 127;
  int rest2 = rest >> 7;
  int hh = rest2 & 1;
  int ksp = rest2 >> 1;             // 0..NKS-1
  int q0 = qt * 16;
  int t = threadIdx.x, w = t >> 6, l = t & 63;
  int l15 = l & 15, lg = l >> 4;
  int h = hh * 4 + w;

  bf16x8 qa0 = *(const bf16x8*)(q + ((size_t)(b * 2048 + q0 + l15) * 512 + h * 64 + lg * 8));
  bf16x8 qa1 = *(const bf16x8*)(q + ((size_t)(b * 2048 + q0 + l15) * 512 + h * 64 + 32 + lg * 8));

  union { bf16x8 v; unsigned short s[8]; } uo;
#pragma unroll
  for (int j = 0; j < 8; ++j) uo.s[j] = 0x3F80;  // bf16 1.0
  const bf16x8 vones = uo.v;

  f32x4 oacc[4] = {};
  f32x4 lacc = {};

  const int kbase0 = ksp * (2048 / NKS);
  const int ITERS = 2048 / NKS / 32;

  const unsigned short* krow = kk + ((size_t)(b * 2048) + l15) * 512 + h * 64 + lg * 8;
  const unsigned short* vrow = vt + (((size_t)(b * 8 + h) * 64) + l15) * 2048 + lg * 8;
  const unsigned short* brow =
      biasT + ((size_t)((b * 8 + h) * 2048 + q0 + lg * 4)) * 2048 + l15 * 2;

  bf16x8 kA[4], vA[4], kB[4], vB[4];
  unsigned bwA[4], bwB[4];

#define LOADT(KR, VR, BW, kb)                                              \
  do {                                                                     \
    KR[0] = *(const bf16x8*)(krow + (size_t)(kb) * 512);                   \
    KR[1] = *(const bf16x8*)(krow + (size_t)(kb) * 512 + 32);              \
    KR[2] = *(const bf16x8*)(krow + (size_t)((kb) + 16) * 512);            \
    KR[3] = *(const bf16x8*)(krow + (size_t)((kb) + 16) * 512 + 32);       \
    BW[0] = *(const unsigned*)(brow + (kb));                               \
    BW[1] = *(const unsigned*)(brow + 2048 + (kb));                        \
    BW[2] = *(const unsigned*)(brow + 4096 + (kb));                        \
    BW[3] = *(const unsigned*)(brow + 6144 + (kb));                        \
    VR[0] = *(const bf16x8*)(vrow + (kb));                                 \
    VR[1] = *(const bf16x8*)(vrow + 16 * 2048 + (kb));                     \
    VR[2] = *(const bf16x8*)(vrow + 32 * 2048 + (kb));                     \
    VR[3] = *(const bf16x8*)(vrow + 48 * 2048 + (kb));                     \
  } while (0)

#define STEP(KR, VR, BW, pb)                                               \
  do {                                                                     \
    f32x4 sc0 = {}, sc1 = {};                                              \
    sc0 = mfma16(qa0, KR[0], sc0);                                         \
    sc0 = mfma16(qa1, KR[1], sc0);                                         \
    sc1 = mfma16(qa0, KR[2], sc1);                                         \
    sc1 = mfma16(qa1, KR[3], sc1);                                         \
    _Pragma("unroll") for (int r = 0; r < 4; ++r) {                        \
      float p0 = __expf(sc0[r] + bs2f((unsigned short)(BW[r] & 0xffff)) - 8.0f); \
      float p1 = __expf(sc1[r] + bs2f((unsigned short)(BW[r] >> 16)) - 8.0f);    \
      ls_p[pb][w][lg * 4 + r][l15] = f2bs(p0);                             \
      ls_p[pb][w][lg * 4 + r][16 + l15] = f2bs(p1);                        \
    }                                                                      \
    bf16x8 pa = *(const bf16x8*)&ls_p[pb][w][l15][lg * 8];                 \
    oacc[0] = mfma16(pa, VR[0], oacc[0]);                                  \
    oacc[1] = mfma16(pa, VR[1], oacc[1]);                                  \
    oacc[2] = mfma16(pa, VR[2], oacc[2]);                                  \
    oacc[3] = mfma16(pa, VR[3], oacc[3]);                                  \
    lacc = mfma16(pa, vones, lacc);                                        \
  } while (0)

  for (int it = 0; it < ITERS; it += 2) {
    int kbA = kbase0 + it * 32;
    int kbB = kbase0 + (it + 1) * 32;
    // ---- pinned burst: all 24 loads of both chains issued before any compute ----
    SB;
    LOADT(kA, vA, bwA, kbA);
    LOADT(kB, vB, bwB, kbB);
    SB;
    STEP(kA, vA, bwA, 0);
    STEP(kB, vB, bwB, 1);
  }
#undef LOADT
#undef STEP

#pragma unroll
  for (int d = 0; d < 4; ++d)
#pragma unroll
    for (int r = 0; r < 4; ++r) {
      size_t row = (size_t)(ksp * 4096 + b * 2048 + q0 + lg * 4 + r);
      opart[row * 512 + h * 64 + d * 16 + l15] = f2bs(oacc[d][r]);
    }
  if (l15 == 0) {
#pragma unroll
    for (int r = 0; r < 4; ++r) {
      size_t row = (size_t)(ksp * 4096 + b * 2048 + q0 + lg * 4 + r);
      lpart[row * 8 + h] = lacc[r];
    }
  }
}

// ---------------- combine k-split partials (static-max: plain sums) ----------------
template <int NKS>
__global__ __launch_bounds__(256) void k_comb2(const unsigned short* __restrict__ op,
                                               const float* __restrict__ lp,
                                               unsigned short* __restrict__ ao) {
  int row = blockIdx.x, t = threadIdx.x;
  for (int c = t; c < 512; c += 256) {
    int h = c >> 6;
    float L = 0.f, o = 0.f;
#pragma unroll
    for (int s = 0; s < NKS; ++s) {
      L += lp[(size_t)(s * 4096 + row) * 8 + h];
      o += bs2f(op[(size_t)(s * 4096 + row) * 512 + c]);
    }
    ao[(size_t)row * 512 + c] = f2bs(o / L);
  }
}

extern "C" void kernel_launch(void* const* d_in, const int* in_sizes, int n_in,
                              void* d_out, int out_size, void* d_ws, size_t ws_size,
                              hipStream_t stream) {
  (void)in_sizes; (void)n_in; (void)out_size; (void)ws_size;
  const float* x = (const float*)d_in[0];
  const float* abias = (const float*)d_in[1];
  const unsigned char* amask = (const unsigned char*)d_in[2];
  const float* Wq = (const float*)d_in[3];
  const float* bq = (const float*)d_in[4];
  const float* Wk = (const float*)d_in[5];
  const float* bk = (const float*)d_in[6];
  const float* Wv = (const float*)d_in[7];
  const float* bv = (const float*)d_in[8];
  const float* Wg = (const float*)d_in[9];
  const float* bg = (const float*)d_in[10];
  const float* Wo = (const float*)d_in[11];
  const float* bo = (const float*)d_in[12];
  const float* ln1g = (const float*)d_in[13];
  const float* ln1b = (const float*)d_in[14];
  const float* ln2g = (const float*)d_in[15];
  const float* ln2b = (const float*)d_in[16];
  const float* W1 = (const float*)d_in[17];
  const float* b1 = (const float*)d_in[18];
  const float* W2 = (const float*)d_in[19];
  const float* b2 = (const float*)d_in[20];
  float* outp = (float*)d_out;

  char* ws = (char*)d_ws;
  const size_t MB = 1024 * 1024;

  unsigned short* qb = (unsigned short*)(ws + 0);          // 4MB [4096][512]
  unsigned short* kb = (unsigned short*)(ws + 4 * MB);     // 4MB
  unsigned short* ao = (unsigned short*)(ws + 8 * MB);     // 4MB
  unsigned short* opart = (unsigned short*)(ws + 12 * MB); // 8MB [2][4096][512]
  unsigned short* y1 = (unsigned short*)(ws + 28 * MB);    // 4MB
  unsigned short* h1 = (unsigned short*)(ws + 0);          // 16MB FFN phase
  float* u = (float*)(ws + 32 * MB);                       // 8MB
  unsigned short* wcat = (unsigned short*)(ws + 40 * MB);  // 2MB
  unsigned short* wot = (unsigned short*)(ws + 42 * MB);   // 0.5MB
  unsigned short* w1t = (unsigned short*)(ws + 42 * MB + 512 * 1024);
  unsigned short* w2t = (unsigned short*)(ws + 44 * MB + 512 * 1024);
  float* bcat = (float*)(ws + 46 * MB + 512 * 1024);
  float* lpart = (float*)(ws + 47 * MB);                   // 512KB [2][4096][8]
  unsigned short* vtb = (unsigned short*)(ws + 48 * MB);   // 4MB [2][8][64][2048]
  unsigned short* biasT = (unsigned short*)(ws + 64 * MB); // 128MB
  float* x2 = (float*)d_out;

  k_transw<<<dim3(8, 8), 256, 0, stream>>>(Wq, wcat + 0 * 512 * 512, 512, 512);
  k_transw<<<dim3(8, 8), 256, 0, stream>>>(Wk, wcat + 1 * 512 * 512, 512, 512);
  k_transw<<<dim3(8, 8), 256, 0, stream>>>(Wv, wcat + 2 * 512 * 512, 512, 512);
  k_transw<<<dim3(8, 8), 256, 0, stream>>>(Wg, wcat + 3 * 512 * 512, 512, 512);
  k_transw<<<dim3(8, 8), 256, 0, stream>>>(Wo, wot, 512, 512);
  k_transw<<<dim3(8, 32), 256, 0, stream>>>(W1, w1t, 512, 2048);
  k_transw<<<dim3(32, 8), 256, 0, stream>>>(W2, w2t, 2048, 512);
  k_bcat<<<8, 256, 0, stream>>>(bq, bk, bv, bg, bcat);

  // bias transpose (roofline streaming pass) overlaps the projection GEMM below
  k_btrans2<<<4096, 256, 0, stream>>>(abias, amask, biasT);

  k_ln<<<4096, 256, 0, stream>>>(x, ln1g, ln1b, y1);
  k_gemm<128><<<dim3(32, 32), 256, 0, stream>>>(y1, wcat, bcat, 4096, 2048, 512, 6,
                                                u, qb, nullptr, nullptr, vtb);
  k_attn13<2><<<1024, 256, 0, stream>>>(qb, kb, vtb, biasT, opart, lpart);
  k_comb2<2><<<4096, 256, 0, stream>>>(opart, lpart, ao);
  k_gemm<64><<<dim3(64, 8), 256, 0, stream>>>(ao, wot, bo, 4096, 512, 512, 3,
                                              x2, nullptr, u, x, nullptr);
  k_ln<<<4096, 256, 0, stream>>>(x2, ln2g, ln2b, y1);
  k_gemm<128><<<dim3(32, 32), 256, 0, stream>>>(y1, w1t, b1, 4096, 2048, 512, 4,
                                                nullptr, h1, nullptr, nullptr, nullptr);
  k_gemm<64><<<dim3(64, 8), 256, 0, stream>>>(h1, w2t, b2, 4096, 512, 2048, 5,
                                              outp, nullptr, x2, nullptr, nullptr);
}

// Round 15
// 268.957 us; speedup vs baseline: 1.3204x; 1.3204x over previous
//
#include <hip/hip_runtime.h>
#include <hip/hip_bf16.h>

#define DI __device__ __forceinline__

typedef __attribute__((ext_vector_type(8))) __bf16 bf16x8;
typedef __attribute__((ext_vector_type(4))) float f32x4;
typedef __attribute__((ext_vector_type(4))) unsigned short u16x4;
typedef __attribute__((ext_vector_type(8))) unsigned short u16x8;

DI unsigned short f2bs(float f) {
  __hip_bfloat16 h = __float2bfloat16(f);
  return __builtin_bit_cast(unsigned short, h);
}
DI float bs2f(unsigned short s) {
  return __bfloat162float(__builtin_bit_cast(__hip_bfloat16, s));
}
DI f32x4 mfma16(bf16x8 a, bf16x8 b, f32x4 c) {
  return __builtin_amdgcn_mfma_f32_16x16x32_bf16(a, b, c, 0, 0, 0);
}
DI void g2lds16(const void* g, void* l) {
  __builtin_amdgcn_global_load_lds(
      (__attribute__((address_space(1))) void*)(unsigned long long)g,
      (__attribute__((address_space(3))) void*)l, 16, 0, 0);
}
#define SB __builtin_amdgcn_sched_barrier(0)
// lgkm-only barrier: does NOT drain vmcnt
DI void barrier_lgkm() {
  asm volatile("s_waitcnt lgkmcnt(0)" ::: "memory");
  SB;
  __builtin_amdgcn_s_barrier();
  SB;
}
// counted guard: drain all but the newest 3 VMEM ops (the 3 bias loads)
DI void vm_guard3() {
  SB;
  asm volatile("s_waitcnt vmcnt(3)" ::: "memory");
  SB;
}

// ---------------- weight transpose f32[K,N] -> bf16[N,K] ----------------
__global__ __launch_bounds__(256) void k_transw(const float* __restrict__ W,
                                                unsigned short* __restrict__ Wt,
                                                int K, int N) {
  __shared__ float tile[64][65];
  int tk = blockIdx.x * 64, tn = blockIdx.y * 64;
  int t = threadIdx.x;
#pragma unroll
  for (int i = 0; i < 16; ++i) {
    int idx = t + i * 256;
    int r = idx >> 6, c = idx & 63;
    tile[r][c] = W[(size_t)(tk + r) * N + tn + c];
  }
  __syncthreads();
#pragma unroll
  for (int i = 0; i < 16; ++i) {
    int idx = t + i * 256;
    int n = idx >> 6, kk = idx & 63;
    Wt[(size_t)(tn + n) * K + tk + kk] = f2bs(tile[kk][n]);
  }
}

// ---------------- bias concat [bq|bk|bv|bg] -> bcat[2048] ----------------
__global__ __launch_bounds__(256) void k_bcat(const float* __restrict__ bq,
                                              const float* __restrict__ bk,
                                              const float* __restrict__ bv,
                                              const float* __restrict__ bg,
                                              float* __restrict__ bcat) {
  int t = blockIdx.x * 256 + threadIdx.x;
  const float* src = t < 512 ? bq : t < 1024 ? bk : t < 1536 ? bv : bg;
  bcat[t] = src[t & 511];
}

// ---------------- LayerNorm f32[rows,512] -> bf16 ----------------
__global__ __launch_bounds__(256) void k_ln(const float* __restrict__ x,
                                            const float* __restrict__ g,
                                            const float* __restrict__ b,
                                            unsigned short* __restrict__ y) {
  int row = blockIdx.x, t = threadIdx.x;
  const float* xr = x + (size_t)row * 512;
  float a0 = xr[t], a1 = xr[t + 256];
  float s1 = a0 + a1, s2 = a0 * a0 + a1 * a1;
#pragma unroll
  for (int o = 32; o > 0; o >>= 1) {
    s1 += __shfl_down(s1, o);
    s2 += __shfl_down(s2, o);
  }
  __shared__ float r1[4], r2[4], bc[2];
  int w = t >> 6, l = t & 63;
  if (l == 0) { r1[w] = s1; r2[w] = s2; }
  __syncthreads();
  if (t == 0) {
    float t1 = r1[0] + r1[1] + r1[2] + r1[3];
    float t2 = r2[0] + r2[1] + r2[2] + r2[3];
    float m = t1 / 512.f;
    float v = t2 / 512.f - m * m;
    bc[0] = m;
    bc[1] = rsqrtf(v + 1e-5f);
  }
  __syncthreads();
  float m = bc[0], inv = bc[1];
  y[(size_t)row * 512 + t] = f2bs((a0 - m) * inv * g[t] + b[t]);
  y[(size_t)row * 512 + t + 256] = f2bs((a1 - m) * inv * g[t + 256] + b[t + 256]);
}

// ---------------- GEMM: C[M,N] = A[M,K](bf16) * Bt[N,K]^T + bias ----------------
template <int BM>
__global__ __launch_bounds__(256) void k_gemm(
    const unsigned short* __restrict__ A, const unsigned short* __restrict__ Bt,
    const float* __restrict__ bias, int M, int N, int K, int mode,
    float* __restrict__ outf, unsigned short* __restrict__ outh,
    const float* __restrict__ add1, const float* __restrict__ add2,
    unsigned short* __restrict__ vtout) {
  constexpr int MI = BM / 32;
  __shared__ __align__(16) unsigned short lA[BM * 64];
  __shared__ __align__(16) unsigned short lB[64 * 64];
  int t = threadIdx.x, w = t >> 6, l = t & 63;
  int l15 = l & 15, lg = l >> 4;
  int m0 = blockIdx.x * BM, n0 = blockIdx.y * 64;
  int wm = (w >> 1) * (BM / 2), wn = (w & 1) * 32;
  f32x4 acc[MI][2] = {};
  int sr = l >> 3, scb = (l & 7) * 16;
  for (int k0 = 0; k0 < K; k0 += 64) {
#pragma unroll
    for (int c = 0; c < MI; ++c) {
      int row = w * (BM / 4) + sr + c * 8;
      g2lds16((const char*)A + ((size_t)(m0 + row) * K + k0) * 2 + scb,
              (char*)lA + w * (BM / 4) * 128 + c * 1024);
    }
#pragma unroll
    for (int c = 0; c < 2; ++c) {
      int row = w * 16 + sr + c * 8;
      g2lds16((const char*)Bt + ((size_t)(n0 + row) * K + k0) * 2 + scb,
              (char*)lB + w * 2048 + c * 1024);
    }
    __syncthreads();
#pragma unroll
    for (int kc = 0; kc < 2; ++kc) {
      bf16x8 af[MI], bfr[2];
#pragma unroll
      for (int i = 0; i < MI; ++i)
        af[i] = *(const bf16x8*)((const char*)lA + (wm + i * 16 + l15) * 128 + kc * 64 + lg * 16);
#pragma unroll
      for (int j = 0; j < 2; ++j)
        bfr[j] = *(const bf16x8*)((const char*)lB + (wn + j * 16 + l15) * 128 + kc * 64 + lg * 16);
#pragma unroll
      for (int i = 0; i < MI; ++i)
#pragma unroll
        for (int j = 0; j < 2; ++j)
          acc[i][j] = mfma16(af[i], bfr[j], acc[i][j]);
    }
    __syncthreads();
  }
#pragma unroll
  for (int i = 0; i < MI; ++i) {
#pragma unroll
    for (int j = 0; j < 2; ++j) {
      int col = n0 + wn + j * 16 + l15;
      int row0 = m0 + wm + i * 16 + lg * 4;
      float vals[4];
#pragma unroll
      for (int r = 0; r < 4; ++r) vals[r] = acc[i][j][r] + bias[col];
      if (mode == 6) {
        int sel = col >> 9, c5 = col & 511;
        if (sel == 2) {
          int hh = c5 >> 6, dd = c5 & 63, bb = row0 >> 11, nn = row0 & 2047;
          u16x4 pk;
#pragma unroll
          for (int r = 0; r < 4; ++r) pk[r] = f2bs(vals[r]);
          *(u16x4*)(vtout + (((size_t)(bb * 8 + hh) * 64 + dd) * 2048 + nn)) = pk;
        } else {
#pragma unroll
          for (int r = 0; r < 4; ++r) {
            size_t idx = (size_t)(row0 + r) * 512 + c5;
            if (sel == 0) outh[idx] = f2bs(vals[r] * 0.125f);
            else if (sel == 1) outh[2097152 + idx] = f2bs(vals[r]);
            else outf[idx] = bs2f(A[idx]) * (1.f / (1.f + __expf(-vals[r])));
          }
        }
      } else {
#pragma unroll
        for (int r = 0; r < 4; ++r) {
          size_t idx = (size_t)(row0 + r) * N + col;
          if (mode == 3) outf[idx] = vals[r] + add1[idx] + add2[idx];
          else if (mode == 4) outh[idx] = f2bs(0.5f * vals[r] * (1.f + erff(vals[r] * 0.70710678f)));
          else outf[idx] = vals[r] + add1[idx];
        }
      }
    }
  }
}

// ---------------- flash attention v14: attn7 + full-iter bias prefetch + counted vmcnt ----------------
// = R7's k_attn7 (fused bias, LDS-staged K/V, 8 waves = 8 heads, grid 256) with:
// (1) bias loaded 2 tiles ahead -> WRITEB consumes regs loaded a full iter earlier;
// (2) STAGEKV-then-LOADB order pinned by sched_barrier; s_waitcnt vmcnt(3) + lgkm-only
//     s_barrier drains exactly the 8 K/V stages, leaving the 3 bias HBM loads in flight.
__global__ __launch_bounds__(512, 1) void k_attn14(
    const unsigned short* __restrict__ q, const unsigned short* __restrict__ kk,
    const unsigned short* __restrict__ vt, const float* __restrict__ bias,
    const unsigned char* __restrict__ mask, unsigned short* __restrict__ ao) {
  __shared__ __align__(16) char lsK[2][32768];   // [buf][row*1024 + swz colbyte]
  __shared__ __align__(16) char lsV[2][32768];   // [buf][((h*64+d)*4 + slot)*16 + ...]
  __shared__ __align__(16) char lsB[2][16 * 520];// [buf][q*520 + k*16 + h*2]
  __shared__ __align__(16) unsigned short ls_p[8][16][36];

  int bid = blockIdx.x;
  int b = bid >> 7, qt = bid & 127;
  int q0 = qt * 16;
  int t = threadIdx.x, w = t >> 6, l = t & 63;
  int l15 = l & 15, lg = l >> 4;
  int h = w;

  bf16x8 qa0 = *(const bf16x8*)(q + ((size_t)(b * 2048 + q0 + l15) * 512 + h * 64 + lg * 8));
  bf16x8 qa1 = *(const bf16x8*)(q + ((size_t)(b * 2048 + q0 + l15) * 512 + h * 64 + 32 + lg * 8));

  union { bf16x8 v; unsigned short s[8]; } uo;
#pragma unroll
  for (int j = 0; j < 8; ++j) uo.s[j] = 0x3F80;  // bf16 1.0
  const bf16x8 vones = uo.v;

  f32x4 oacc[4] = {};
  f32x4 lacc = {};

  // ---- staging source pointers ----
  const char* kptr[4];
  char* kdst[4];
#pragma unroll
  for (int i = 0; i < 4; ++i) {
    int fi = t + i * 512;
    int row = fi >> 6;
    int colb = ((fi & 63) * 16) ^ ((row & 7) << 4);
    kptr[i] = (const char*)kk + ((size_t)(b * 2048 + row) * 512) * 2 + colb;
    kdst[i] = (char*)0 + (i * 512 + w * 64) * 16;
  }
  const char* vptr[4];
#pragma unroll
  for (int i = 0; i < 4; ++i) {
    int fi = t + i * 512;
    int rv = fi >> 2;
    int dv = rv & 63, hv = rv >> 6;
    int slot = (fi & 3) ^ (dv & 3);
    vptr[i] = (const char*)vt + (((size_t)(b * 8 + hv) * 64 + dv) * 2048 + slot * 8) * 2;
  }
  int qq = t >> 5, kc = t & 31;
  const float* bptr = bias + ((size_t)(b * 2048 + q0 + qq) * 2048 + kc) * 8;
  const unsigned char* mptr = mask + (size_t)(b * 2048 + q0 + qq) * 2048 + kc;
  char* bdst = (char*)0 + qq * 520 + kc * 16;
  const unsigned short BN = f2bs(-1e30f);

#define STAGEKV(buf, kb)                                                     \
  do {                                                                       \
    _Pragma("unroll") for (int i = 0; i < 4; ++i)                            \
        g2lds16(kptr[i] + (size_t)(kb) * 1024, lsK[buf] + (size_t)kdst[i]);  \
    _Pragma("unroll") for (int i = 0; i < 4; ++i)                            \
        g2lds16(vptr[i] + (size_t)(kb) * 2, lsV[buf] + (size_t)kdst[i]);     \
  } while (0)
#define LOADB(BA, BB, MB, kb)                                                \
  do {                                                                       \
    BA = *(const float4*)(bptr + (size_t)(kb) * 8);                          \
    BB = *(const float4*)(bptr + (size_t)(kb) * 8 + 4);                      \
    MB = mptr[kb];                                                           \
  } while (0)
#define WRITEB(buf, BA, BB, MB)                                              \
  do {                                                                       \
    u16x8 o;                                                                 \
    if (MB) {                                                                \
      _Pragma("unroll") for (int j = 0; j < 8; ++j) o[j] = BN;               \
    } else {                                                                 \
      o[0] = f2bs(BA.x); o[1] = f2bs(BA.y); o[2] = f2bs(BA.z);               \
      o[3] = f2bs(BA.w); o[4] = f2bs(BB.x); o[5] = f2bs(BB.y);               \
      o[6] = f2bs(BB.z); o[7] = f2bs(BB.w);                                  \
    }                                                                        \
    *(u16x8*)(lsB[buf] + (size_t)bdst) = o;                                  \
  } while (0)
#define LDSK(buf, tt, kcc)                                                   \
  (*(const bf16x8*)(lsK[buf] + ((tt)*16 + l15) * 1024 +                      \
                    ((h * 128 + (kcc)*64 + lg * 16) ^ ((((tt)*16 + l15) & 7) << 4))))
#define LDSV(buf, dt)                                                        \
  (*(const bf16x8*)(lsV[buf] +                                               \
                    (((h * 64 + (dt)*16 + l15) * 4 +                         \
                      (lg ^ (((dt)*16 + l15) & 3))) * 16)))
#define COMPUTE(buf)                                                         \
  do {                                                                       \
    f32x4 sc0 = {}, sc1 = {};                                                \
    sc0 = mfma16(qa0, LDSK(buf, 0, 0), sc0);                                 \
    sc0 = mfma16(qa1, LDSK(buf, 0, 1), sc0);                                 \
    sc1 = mfma16(qa0, LDSK(buf, 1, 0), sc1);                                 \
    sc1 = mfma16(qa1, LDSK(buf, 1, 1), sc1);                                 \
    _Pragma("unroll") for (int r = 0; r < 4; ++r) {                          \
      int qr = lg * 4 + r;                                                   \
      float b0 = bs2f(*(const unsigned short*)(lsB[buf] + qr * 520 + l15 * 16 + h * 2));          \
      float b1 = bs2f(*(const unsigned short*)(lsB[buf] + qr * 520 + (l15 + 16) * 16 + h * 2));   \
      float p0 = __expf(sc0[r] + b0 - 8.0f);                                 \
      float p1 = __expf(sc1[r] + b1 - 8.0f);                                 \
      ls_p[w][qr][l15] = f2bs(p0);                                           \
      ls_p[w][qr][16 + l15] = f2bs(p1);                                      \
    }                                                                        \
    bf16x8 pa = *(const bf16x8*)&ls_p[w][l15][lg * 8];                       \
    oacc[0] = mfma16(pa, LDSV(buf, 0), oacc[0]);                             \
    oacc[1] = mfma16(pa, LDSV(buf, 1), oacc[1]);                             \
    oacc[2] = mfma16(pa, LDSV(buf, 2), oacc[2]);                             \
    oacc[3] = mfma16(pa, LDSV(buf, 3), oacc[3]);                             \
    lacc = mfma16(pa, vones, lacc);                                          \
  } while (0)

  float4 rA0, rA1, rB0, rB1;
  unsigned char mA, mB;
  // prologue: bias(0) -> buf0 (one-time stall ok); bias(1) -> regs B; K/V(0) -> buf0
  LOADB(rA0, rA1, mA, 0);
  WRITEB(0, rA0, rA1, mA);
  LOADB(rB0, rB1, mB, 32);
  SB;
  STAGEKV(0, 0);
  SB;
  vm_guard3();       // drains the 8 stages; rB bias loads stay in flight
  barrier_lgkm();
  for (int it = 0; it < 64; it += 2) {
    int kb1 = (it + 1) * 32;                         // it+1 <= 63 always valid
    int kb2 = (it + 2 < 64) ? (it + 2) * 32 : 0;
    int kb3 = (it + 3 < 64) ? (it + 3) * 32 : 0;
    // ---- half A: consume buf0(it); stage buf1(it+1); load bias(it+2) ----
    SB;
    STAGEKV(1, kb1);
    SB;
    LOADB(rA0, rA1, mA, kb2);
    SB;
    COMPUTE(0);
    WRITEB(1, rB0, rB1, mB);    // bias(it+1), loaded a full iter ago
    vm_guard3();
    barrier_lgkm();
    // ---- half B: consume buf1(it+1); stage buf0(it+2); load bias(it+3) ----
    SB;
    STAGEKV(0, kb2);
    SB;
    LOADB(rB0, rB1, mB, kb3);
    SB;
    COMPUTE(1);
    WRITEB(0, rA0, rA1, mA);    // bias(it+2)
    vm_guard3();
    barrier_lgkm();
  }
#undef STAGEKV
#undef LOADB
#undef WRITEB
#undef LDSK
#undef LDSV
#undef COMPUTE

#pragma unroll
  for (int d = 0; d < 4; ++d)
#pragma unroll
    for (int r = 0; r < 4; ++r) {
      size_t row = (size_t)(b * 2048 + q0 + lg * 4 + r);
      ao[row * 512 + h * 64 + d * 16 + l15] = f2bs(oacc[d][r] / lacc[r]);
    }
}

extern "C" void kernel_launch(void* const* d_in, const int* in_sizes, int n_in,
                              void* d_out, int out_size, void* d_ws, size_t ws_size,
                              hipStream_t stream) {
  (void)in_sizes; (void)n_in; (void)out_size; (void)ws_size;
  const float* x = (const float*)d_in[0];
  const float* abias = (const float*)d_in[1];
  const unsigned char* amask = (const unsigned char*)d_in[2];
  const float* Wq = (const float*)d_in[3];
  const float* bq = (const float*)d_in[4];
  const float* Wk = (const float*)d_in[5];
  const float* bk = (const float*)d_in[6];
  const float* Wv = (const float*)d_in[7];
  const float* bv = (const float*)d_in[8];
  const float* Wg = (const float*)d_in[9];
  const float* bg = (const float*)d_in[10];
  const float* Wo = (const float*)d_in[11];
  const float* bo = (const float*)d_in[12];
  const float* ln1g = (const float*)d_in[13];
  const float* ln1b = (const float*)d_in[14];
  const float* ln2g = (const float*)d_in[15];
  const float* ln2b = (const float*)d_in[16];
  const float* W1 = (const float*)d_in[17];
  const float* b1 = (const float*)d_in[18];
  const float* W2 = (const float*)d_in[19];
  const float* b2 = (const float*)d_in[20];
  float* outp = (float*)d_out;

  char* ws = (char*)d_ws;
  const size_t MB = 1024 * 1024;

  unsigned short* qb = (unsigned short*)(ws + 0);          // 4MB [4096][512]
  unsigned short* kb = (unsigned short*)(ws + 4 * MB);     // 4MB
  unsigned short* ao = (unsigned short*)(ws + 8 * MB);     // 4MB
  unsigned short* y1 = (unsigned short*)(ws + 28 * MB);    // 4MB
  unsigned short* h1 = (unsigned short*)(ws + 0);          // 16MB FFN phase
  float* u = (float*)(ws + 32 * MB);                       // 8MB
  unsigned short* wcat = (unsigned short*)(ws + 40 * MB);  // 2MB
  unsigned short* wot = (unsigned short*)(ws + 42 * MB);   // 0.5MB
  unsigned short* w1t = (unsigned short*)(ws + 42 * MB + 512 * 1024);
  unsigned short* w2t = (unsigned short*)(ws + 44 * MB + 512 * 1024);
  float* bcat = (float*)(ws + 46 * MB + 512 * 1024);
  unsigned short* vtb = (unsigned short*)(ws + 48 * MB);   // 4MB [2][8][64][2048]
  float* x2 = (float*)d_out;

  k_transw<<<dim3(8, 8), 256, 0, stream>>>(Wq, wcat + 0 * 512 * 512, 512, 512);
  k_transw<<<dim3(8, 8), 256, 0, stream>>>(Wk, wcat + 1 * 512 * 512, 512, 512);
  k_transw<<<dim3(8, 8), 256, 0, stream>>>(Wv, wcat + 2 * 512 * 512, 512, 512);
  k_transw<<<dim3(8, 8), 256, 0, stream>>>(Wg, wcat + 3 * 512 * 512, 512, 512);
  k_transw<<<dim3(8, 8), 256, 0, stream>>>(Wo, wot, 512, 512);
  k_transw<<<dim3(8, 32), 256, 0, stream>>>(W1, w1t, 512, 2048);
  k_transw<<<dim3(32, 8), 256, 0, stream>>>(W2, w2t, 2048, 512);
  k_bcat<<<8, 256, 0, stream>>>(bq, bk, bv, bg, bcat);

  k_ln<<<4096, 256, 0, stream>>>(x, ln1g, ln1b, y1);
  k_gemm<128><<<dim3(32, 32), 256, 0, stream>>>(y1, wcat, bcat, 4096, 2048, 512, 6,
                                                u, qb, nullptr, nullptr, vtb);
  k_attn14<<<256, 512, 0, stream>>>(qb, kb, vtb, abias, amask, ao);
  k_gemm<64><<<dim3(64, 8), 256, 0, stream>>>(ao, wot, bo, 4096, 512, 512, 3,
                                              x2, nullptr, u, x, nullptr);
  k_ln<<<4096, 256, 0, stream>>>(x2, ln2g, ln2b, y1);
  k_gemm<128><<<dim3(32, 32), 256, 0, stream>>>(y1, w1t, b1, 4096, 2048, 512, 4,
                                                nullptr, h1, nullptr, nullptr, nullptr);
  k_gemm<64><<<dim3(64, 8), 256, 0, stream>>>(h1, w2t, b2, 4096, 512, 2048, 5,
                                              outp, nullptr, x2, nullptr, nullptr);
}